// Round 2
// baseline (443.028 us; speedup 1.0000x reference)
//
#include <hip/hip_runtime.h>

// MAUCHLoss: B=2097152 rows, C=15 categories, f32 inputs.
// ws layout: [0..14] sum(sig) per cat, [15..29] sum(sig*label),
// [30..44] sum(label) (npos), [45] sum(sp + (1-label)*sig) for CEL,
// [46] (as uint) block-done counter for the last-block finalize.

#define CATS 15
#define NBLOCKS 1920  // 1920*256*4 = 1,966,080 = 15*131072 -> per-thread category phase constant
                      // 1920 blocks = 30 waves/CU at VGPR~20 -> near-full occupancy
#define NTHREADS 256
#define NSUMS (3 * CATS + 1)   // 46

__device__ __forceinline__ void accum_elem(float x, float l,
                                           float& ssig, float& spos, float& snp,
                                           float& cel) {
    // sig = sigmoid(x)
    float e   = __expf(-x);
    float sig = __builtin_amdgcn_rcpf(1.0f + e);
    // sp = log(1 + exp(-sig)) = -log(sigmoid(sig)); sig in (0,1) -> stable
    float sp  = __logf(1.0f + __expf(-sig));
    ssig += sig;
    spos += sig * l;
    snp  += l;
    cel  += sp + (1.0f - l) * sig;
}

__global__ __launch_bounds__(NTHREADS) void mauch_main(
    const float* __restrict__ outp, const float* __restrict__ labp,
    float* __restrict__ ws, float* __restrict__ out,
    int nFloat4, float invBC, float rowsB)
{
    const int t = blockIdx.x * blockDim.x + threadIdx.x;
    const int stride = gridDim.x * blockDim.x;   // stride*4 % 15 == 0

    float ssig[4] = {0.f, 0.f, 0.f, 0.f};
    float spos[4] = {0.f, 0.f, 0.f, 0.f};
    float snp[4]  = {0.f, 0.f, 0.f, 0.f};
    float cel = 0.f;

    const float4* o4 = (const float4*)outp;
    const float4* l4 = (const float4*)labp;

    const int iters = nFloat4 / stride;          // 16 for the fixed problem size

    // software-pipelined grid-stride loop: prefetch next iter's loads
    float4 ov = o4[t];
    float4 lv = l4[t];
    for (int i = 1; i <= iters; ++i) {
        float4 co = ov, cl = lv;
        if (i < iters) {
            int fn = t + i * stride;
            ov = o4[fn];
            lv = l4[fn];
        }
#pragma unroll
        for (int j = 0; j < 4; ++j)
            accum_elem((&co.x)[j], (&cl.x)[j], ssig[j], spos[j], snp[j], cel);
    }
    // tail (none when stride divides nFloat4, kept for generality)
    int ft = t + iters * stride;
    if (ft < nFloat4) {
        float4 co = o4[ft];
        float4 cl = l4[ft];
#pragma unroll
        for (int j = 0; j < 4; ++j)
            accum_elem((&co.x)[j], (&cl.x)[j], ssig[j], spos[j], snp[j], cel);
    }

    // ---- block reduction in LDS ----
    __shared__ float red[NSUMS];
    for (int i = threadIdx.x; i < NSUMS; i += blockDim.x) red[i] = 0.f;
    __syncthreads();

    // element categories for this thread: (4t + j) mod 15, constant across iterations
    int base = (4 * t) % CATS;
#pragma unroll
    for (int j = 0; j < 4; ++j) {
        int c = base + j; if (c >= CATS) c -= CATS;
        atomicAdd(&red[c],            ssig[j]);
        atomicAdd(&red[CATS + c],     spos[j]);
        atomicAdd(&red[2 * CATS + c], snp[j]);
    }
    atomicAdd(&red[3 * CATS], cel);
    __syncthreads();

    // ---- global accumulation (device-scope atomics) ----
    if (threadIdx.x < NSUMS) atomicAdd(&ws[threadIdx.x], red[threadIdx.x]);
    __threadfence();
    __syncthreads();

    // ---- last-block-done finalize ----
    __shared__ int isLast;
    if (threadIdx.x == 0) {
        unsigned int* ctr = (unsigned int*)(ws + NSUMS);
        isLast = (atomicAdd(ctr, 1u) == (unsigned int)(gridDim.x - 1));
    }
    __syncthreads();
    if (isLast) {
        // coherent reads of the fully-accumulated sums via fetch-add 0
        if (threadIdx.x < NSUMS) red[threadIdx.x] = atomicAdd(&ws[threadIdx.x], 0.0f);
        __syncthreads();
        if (threadIdx.x == 0) {
            float sum_term = 0.f, pen_last = 0.f;
#pragma unroll
            for (int c = 0; c < CATS; ++c) {
                float s   = red[c];
                float sp  = red[CATS + c];
                float np  = red[2 * CATS + c];
                float nn  = rowsB - np;
                float sneg = s - sp;
                float mp = (np > 0.f) ? sp   / fmaxf(np, 1.f) : 0.f;
                float mn = (nn > 0.f) ? sneg / fmaxf(nn, 1.f) : 0.f;
                float pen = 1.f - mp + mn;
                sum_term += pen;
                if (c == CATS - 1) pen_last = pen;
            }
            float celv = red[3 * CATS] * invBC;
            out[0] = celv + 0.1f * (sum_term / 15.f);
            out[1] = 0.1f * pen_last;
        }
    }
}

extern "C" void kernel_launch(void* const* d_in, const int* in_sizes, int n_in,
                              void* d_out, int out_size, void* d_ws, size_t ws_size,
                              hipStream_t stream) {
    const float* outp = (const float*)d_in[0];
    const float* labp = (const float*)d_in[1];
    float* out = (float*)d_out;
    float* ws  = (float*)d_ws;

    const int total   = in_sizes[0];          // B * 15
    const int nFloat4 = total / 4;
    const float rowsB = (float)(total / CATS);
    const float invBC = 1.0f / (float)total;

    // ws re-poisoned before every timed launch -> zero sums + done-counter
    hipMemsetAsync(ws, 0, (NSUMS + 1) * sizeof(float), stream);

    mauch_main<<<NBLOCKS, NTHREADS, 0, stream>>>(outp, labp, ws, out,
                                                 nFloat4, invBC, rowsB);
}

// Round 3
// 276.999 us; speedup vs baseline: 1.5994x; 1.5994x over previous
//
#include <hip/hip_runtime.h>

// MAUCHLoss: B=2097152 rows, C=15 categories, f32 inputs.
// ws layout (46 floats): [0..14] sum(sig) per cat, [15..29] sum(sig*label),
// [30..44] sum(label) (npos), [45] sum(sp + (1-label)*sig) for CEL.
//
// R2 post-mortem: __threadfence + merged finalize was a 3x regression
// (TCC-serialized fences, VALUBusy 21->8%). Keep the kernel fence-free;
// finalize stays a separate 1-block kernel.

#define CATS 15
#define NBLOCKS 1920  // 1920*256*4 = 1,966,080 = 15*131072 -> per-thread category phase constant
#define NTHREADS 256
#define NSUMS (3 * CATS + 1)   // 46

__device__ __forceinline__ void accum_elem(float x, float l,
                                           float& ssig, float& spos, float& snp,
                                           float& cel) {
    // sig = sigmoid(x)
    float e   = __expf(-x);
    float sig = __builtin_amdgcn_rcpf(1.0f + e);
    // sp = log(1 + exp(-sig)) = -log(sigmoid(sig)); sig in (0,1) -> stable
    float sp  = __logf(1.0f + __expf(-sig));
    ssig += sig;
    spos += sig * l;
    snp  += l;
    cel  += sp + (1.0f - l) * sig;
}

__global__ __launch_bounds__(NTHREADS) void mauch_main(
    const float* __restrict__ outp, const float* __restrict__ labp,
    float* __restrict__ ws, int nFloat4)
{
    const int t = blockIdx.x * blockDim.x + threadIdx.x;
    const int stride = gridDim.x * blockDim.x;   // stride*4 % 15 == 0

    float ssig[4] = {0.f, 0.f, 0.f, 0.f};
    float spos[4] = {0.f, 0.f, 0.f, 0.f};
    float snp[4]  = {0.f, 0.f, 0.f, 0.f};
    float cel = 0.f;

    const float4* o4 = (const float4*)outp;
    const float4* l4 = (const float4*)labp;

    if (nFloat4 == 16 * stride) {
        // fixed-size fast path: 16 iterations, unroll x4 so the compiler
        // batches 8 dwordx4 loads in flight per thread
#pragma unroll 4
        for (int i = 0; i < 16; ++i) {
            float4 ov = o4[t + i * stride];
            float4 lv = l4[t + i * stride];
#pragma unroll
            for (int j = 0; j < 4; ++j)
                accum_elem((&ov.x)[j], (&lv.x)[j], ssig[j], spos[j], snp[j], cel);
        }
    } else {
        for (int f = t; f < nFloat4; f += stride) {
            float4 ov = o4[f];
            float4 lv = l4[f];
#pragma unroll
            for (int j = 0; j < 4; ++j)
                accum_elem((&ov.x)[j], (&lv.x)[j], ssig[j], spos[j], snp[j], cel);
        }
    }

    // ---- block reduction in LDS ----
    __shared__ float red[NSUMS];
    for (int i = threadIdx.x; i < NSUMS; i += blockDim.x) red[i] = 0.f;
    __syncthreads();

    // element categories for this thread: (4t + j) mod 15, constant across iterations
    int base = (4 * t) % CATS;
#pragma unroll
    for (int j = 0; j < 4; ++j) {
        int c = base + j; if (c >= CATS) c -= CATS;
        atomicAdd(&red[c],            ssig[j]);
        atomicAdd(&red[CATS + c],     spos[j]);
        atomicAdd(&red[2 * CATS + c], snp[j]);
    }
    atomicAdd(&red[3 * CATS], cel);
    __syncthreads();

    // ---- global accumulation (device-scope atomics, no fence) ----
    if (threadIdx.x < NSUMS) atomicAdd(&ws[threadIdx.x], red[threadIdx.x]);
}

__global__ void mauch_final(const float* __restrict__ ws, float* __restrict__ out,
                            float invBC, float rowsB)
{
    if (threadIdx.x == 0 && blockIdx.x == 0) {
        float sum_term = 0.f, pen_last = 0.f;
#pragma unroll
        for (int c = 0; c < CATS; ++c) {
            float ssig = ws[c];
            float sp   = ws[CATS + c];
            float np   = ws[2 * CATS + c];
            float nn   = rowsB - np;
            float sneg = ssig - sp;
            float mp = (np > 0.f) ? sp   / fmaxf(np, 1.f) : 0.f;
            float mn = (nn > 0.f) ? sneg / fmaxf(nn, 1.f) : 0.f;
            float pen = 1.f - mp + mn;
            sum_term += pen;
            if (c == CATS - 1) pen_last = pen;
        }
        float cel = ws[3 * CATS] * invBC;
        out[0] = cel + 0.1f * (sum_term / 15.f);
        out[1] = 0.1f * pen_last;
    }
}

extern "C" void kernel_launch(void* const* d_in, const int* in_sizes, int n_in,
                              void* d_out, int out_size, void* d_ws, size_t ws_size,
                              hipStream_t stream) {
    const float* outp = (const float*)d_in[0];
    const float* labp = (const float*)d_in[1];
    float* out = (float*)d_out;
    float* ws  = (float*)d_ws;

    const int total   = in_sizes[0];          // B * 15
    const int nFloat4 = total / 4;
    const float rowsB = (float)(total / CATS);
    const float invBC = 1.0f / (float)total;

    // ws is re-poisoned before every timed launch -> zero it (capture-safe async memset)
    hipMemsetAsync(ws, 0, NSUMS * sizeof(float), stream);

    mauch_main<<<NBLOCKS, NTHREADS, 0, stream>>>(outp, labp, ws, nFloat4);
    mauch_final<<<1, 64, 0, stream>>>(ws, out, invBC, rowsB);
}

// Round 4
// 269.872 us; speedup vs baseline: 1.6416x; 1.0264x over previous
//
#include <hip/hip_runtime.h>

// MAUCHLoss: B=2097152 rows, C=15 categories, f32 inputs.
// ws layout (46 floats): [0..14] sum(sig) per cat, [15..29] sum(sig*label),
// [30..44] sum(label) (npos), [45] sum(sp + (1-label)*sig) for CEL.
//
// R3 post-mortem: occupancy 35->54% changed nothing (106 vs 108 us) ->
// per-wave MLP-bound, compiler kept only 2 loads in flight (VGPR=36).
// R4: explicit 4-deep register pipeline (8 float4 loads in flight, forced
// by data dependence) + nontemporal loads (single-use streams).

#define CATS 15
#define NBLOCKS 1920  // 1920*256*4 = 1,966,080 = 15*131072 -> category phase constant per thread
#define NTHREADS 256
#define NSUMS (3 * CATS + 1)   // 46
#define PF 4                   // pipeline depth (iterations ahead)
#define ITERS 16               // nFloat4 / stride for the fixed problem size

typedef float vf4 __attribute__((ext_vector_type(4)));

__device__ __forceinline__ vf4 ntload4(const vf4* p) {
    return __builtin_nontemporal_load(p);
}

__device__ __forceinline__ void accum_elem(float x, float l,
                                           float& ssig, float& spos, float& snp,
                                           float& cel) {
    // sig = sigmoid(x)
    float e   = __expf(-x);
    float sig = __builtin_amdgcn_rcpf(1.0f + e);
    // sp = log(1 + exp(-sig)) = -log(sigmoid(sig)); sig in (0,1) -> stable
    float sp  = __logf(1.0f + __expf(-sig));
    ssig += sig;
    spos += sig * l;
    snp  += l;
    cel  += sp + (1.0f - l) * sig;
}

__global__ __launch_bounds__(NTHREADS) void mauch_main(
    const float* __restrict__ outp, const float* __restrict__ labp,
    float* __restrict__ ws, int nFloat4)
{
    const int t = blockIdx.x * blockDim.x + threadIdx.x;
    const int stride = gridDim.x * blockDim.x;   // stride*4 % 15 == 0

    float ssig[4] = {0.f, 0.f, 0.f, 0.f};
    float spos[4] = {0.f, 0.f, 0.f, 0.f};
    float snp[4]  = {0.f, 0.f, 0.f, 0.f};
    float cel = 0.f;

    const vf4* o4 = (const vf4*)outp;
    const vf4* l4 = (const vf4*)labp;

    if (nFloat4 == ITERS * stride) {
        // fixed-size fast path: explicit PF-deep register pipeline
        vf4 ob[PF], lb[PF];
#pragma unroll
        for (int p = 0; p < PF; ++p) {
            ob[p] = ntload4(o4 + t + p * stride);
            lb[p] = ntload4(l4 + t + p * stride);
        }
#pragma unroll
        for (int i = 0; i < ITERS; ++i) {
            vf4 ov = ob[i % PF];
            vf4 lv = lb[i % PF];
            if (i + PF < ITERS) {
                ob[i % PF] = ntload4(o4 + t + (i + PF) * stride);
                lb[i % PF] = ntload4(l4 + t + (i + PF) * stride);
            }
#pragma unroll
            for (int j = 0; j < 4; ++j)
                accum_elem(ov[j], lv[j], ssig[j], spos[j], snp[j], cel);
        }
    } else {
        for (int f = t; f < nFloat4; f += stride) {
            vf4 ov = ntload4(o4 + f);
            vf4 lv = ntload4(l4 + f);
#pragma unroll
            for (int j = 0; j < 4; ++j)
                accum_elem(ov[j], lv[j], ssig[j], spos[j], snp[j], cel);
        }
    }

    // ---- block reduction in LDS ----
    __shared__ float red[NSUMS];
    for (int i = threadIdx.x; i < NSUMS; i += blockDim.x) red[i] = 0.f;
    __syncthreads();

    // element categories for this thread: (4t + j) mod 15, constant across iterations
    int base = (4 * t) % CATS;
#pragma unroll
    for (int j = 0; j < 4; ++j) {
        int c = base + j; if (c >= CATS) c -= CATS;
        atomicAdd(&red[c],            ssig[j]);
        atomicAdd(&red[CATS + c],     spos[j]);
        atomicAdd(&red[2 * CATS + c], snp[j]);
    }
    atomicAdd(&red[3 * CATS], cel);
    __syncthreads();

    // ---- global accumulation (device-scope atomics, no fence) ----
    if (threadIdx.x < NSUMS) atomicAdd(&ws[threadIdx.x], red[threadIdx.x]);
}

__global__ void mauch_final(const float* __restrict__ ws, float* __restrict__ out,
                            float invBC, float rowsB)
{
    if (threadIdx.x == 0 && blockIdx.x == 0) {
        float sum_term = 0.f, pen_last = 0.f;
#pragma unroll
        for (int c = 0; c < CATS; ++c) {
            float ssig = ws[c];
            float sp   = ws[CATS + c];
            float np   = ws[2 * CATS + c];
            float nn   = rowsB - np;
            float sneg = ssig - sp;
            float mp = (np > 0.f) ? sp   / fmaxf(np, 1.f) : 0.f;
            float mn = (nn > 0.f) ? sneg / fmaxf(nn, 1.f) : 0.f;
            float pen = 1.f - mp + mn;
            sum_term += pen;
            if (c == CATS - 1) pen_last = pen;
        }
        float cel = ws[3 * CATS] * invBC;
        out[0] = cel + 0.1f * (sum_term / 15.f);
        out[1] = 0.1f * pen_last;
    }
}

extern "C" void kernel_launch(void* const* d_in, const int* in_sizes, int n_in,
                              void* d_out, int out_size, void* d_ws, size_t ws_size,
                              hipStream_t stream) {
    const float* outp = (const float*)d_in[0];
    const float* labp = (const float*)d_in[1];
    float* out = (float*)d_out;
    float* ws  = (float*)d_ws;

    const int total   = in_sizes[0];          // B * 15
    const int nFloat4 = total / 4;
    const float rowsB = (float)(total / CATS);
    const float invBC = 1.0f / (float)total;

    // ws is re-poisoned before every timed launch -> zero it (capture-safe async memset)
    hipMemsetAsync(ws, 0, NSUMS * sizeof(float), stream);

    mauch_main<<<NBLOCKS, NTHREADS, 0, stream>>>(outp, labp, ws, nFloat4);
    mauch_final<<<1, 64, 0, stream>>>(ws, out, invBC, rowsB);
}

// Round 5
// 259.243 us; speedup vs baseline: 1.7089x; 1.0410x over previous
//
#include <hip/hip_runtime.h>

// MAUCHLoss: B=2097152 rows, C=15 categories, f32 inputs.
// ws layout (46 floats): [0..14] sum(sig) per cat, [15..29] sum(sig*label),
// [30..44] sum(label) (npos), [45] sum(softplus(-sig)) for CEL.
//
// R4 post-mortem: PF=4 register pipeline + nt loads -> 74 us. In-flight
// bytes/CU >> Little's-law need, so remaining time is (a) 1920-block
// two-round tail, (b) 4 transcendentals/element on the critical path.
// R5: 960 blocks (single residency round, ITERS=32), softplus poly
// (2 transcendentals/elem), cel = sum(sp) only (sum((1-l)sig) folded
// into finalize via ssig - spos).

#define CATS 15
#define NBLOCKS 960   // 960*256*4 = 983,040 = 15*65536 -> category phase constant per thread
                      // 960 blocks co-resident in ONE round at VGPR~64 (no tail)
#define NTHREADS 256
#define NSUMS (3 * CATS + 1)   // 46
#define PF 4                   // pipeline depth (iterations ahead)
#define ITERS 32               // nFloat4 / stride for the fixed problem size

typedef float vf4 __attribute__((ext_vector_type(4)));

__device__ __forceinline__ vf4 ntload4(const vf4* p) {
    return __builtin_nontemporal_load(p);
}

// softplus(-s) = log(1+exp(-s)) on s in (0,1): degree-4 minimax-ish poly.
// Taylor ln2 - s/2 + s^2/8 with c4 adjusted to zero the s=1 endpoint error.
// |err| < 1e-4 on (0,1) -- far under the 1.66e-2 output threshold.
__device__ __forceinline__ float softplus_neg_unit(float s) {
    const float c0 = 0.69314718f, c1 = -0.5f, c2 = 0.125f, c4 = -0.0048853f;
    float s2 = s * s;
    return c0 + fmaf(c1, s, fmaf(c2, s2, c4 * s2 * s2));
}

__device__ __forceinline__ void accum_elem(float x, float l,
                                           float& ssig, float& spos, float& snp,
                                           float& scel) {
    float e   = __expf(-x);                       // transcendental 1
    float sig = __builtin_amdgcn_rcpf(1.0f + e);  // transcendental 2
    ssig += sig;
    spos = fmaf(sig, l, spos);
    snp  += l;
    scel += softplus_neg_unit(sig);               // 4 FMA instead of exp+log
}

__global__ __launch_bounds__(NTHREADS) void mauch_main(
    const float* __restrict__ outp, const float* __restrict__ labp,
    float* __restrict__ ws, int nFloat4)
{
    const int t = blockIdx.x * blockDim.x + threadIdx.x;
    const int stride = gridDim.x * blockDim.x;   // stride*4 % 15 == 0

    float ssig[4] = {0.f, 0.f, 0.f, 0.f};
    float spos[4] = {0.f, 0.f, 0.f, 0.f};
    float snp[4]  = {0.f, 0.f, 0.f, 0.f};
    float scel = 0.f;

    const vf4* o4 = (const vf4*)outp;
    const vf4* l4 = (const vf4*)labp;

    if (nFloat4 == ITERS * stride) {
        // fixed-size fast path: explicit PF-deep register pipeline
        vf4 ob[PF], lb[PF];
#pragma unroll
        for (int p = 0; p < PF; ++p) {
            ob[p] = ntload4(o4 + t + p * stride);
            lb[p] = ntload4(l4 + t + p * stride);
        }
#pragma unroll
        for (int i = 0; i < ITERS; ++i) {
            vf4 ov = ob[i % PF];
            vf4 lv = lb[i % PF];
            if (i + PF < ITERS) {
                ob[i % PF] = ntload4(o4 + t + (i + PF) * stride);
                lb[i % PF] = ntload4(l4 + t + (i + PF) * stride);
            }
#pragma unroll
            for (int j = 0; j < 4; ++j)
                accum_elem(ov[j], lv[j], ssig[j], spos[j], snp[j], scel);
        }
    } else {
        for (int f = t; f < nFloat4; f += stride) {
            vf4 ov = ntload4(o4 + f);
            vf4 lv = ntload4(l4 + f);
#pragma unroll
            for (int j = 0; j < 4; ++j)
                accum_elem(ov[j], lv[j], ssig[j], spos[j], snp[j], scel);
        }
    }

    // ---- block reduction in LDS ----
    __shared__ float red[NSUMS];
    for (int i = threadIdx.x; i < NSUMS; i += blockDim.x) red[i] = 0.f;
    __syncthreads();

    // element categories for this thread: (4t + j) mod 15, constant across iterations
    int base = (4 * t) % CATS;
#pragma unroll
    for (int j = 0; j < 4; ++j) {
        int c = base + j; if (c >= CATS) c -= CATS;
        atomicAdd(&red[c],            ssig[j]);
        atomicAdd(&red[CATS + c],     spos[j]);
        atomicAdd(&red[2 * CATS + c], snp[j]);
    }
    atomicAdd(&red[3 * CATS], scel);
    __syncthreads();

    // ---- global accumulation (device-scope atomics, no fence) ----
    if (threadIdx.x < NSUMS) atomicAdd(&ws[threadIdx.x], red[threadIdx.x]);
}

__global__ void mauch_final(const float* __restrict__ ws, float* __restrict__ out,
                            float invBC, float rowsB)
{
    if (threadIdx.x == 0 && blockIdx.x == 0) {
        float sum_term = 0.f, pen_last = 0.f;
        float tot_ssig = 0.f, tot_spos = 0.f;
#pragma unroll
        for (int c = 0; c < CATS; ++c) {
            float ssig = ws[c];
            float sp   = ws[CATS + c];
            float np   = ws[2 * CATS + c];
            float nn   = rowsB - np;
            float sneg = ssig - sp;
            tot_ssig += ssig;
            tot_spos += sp;
            float mp = (np > 0.f) ? sp   / fmaxf(np, 1.f) : 0.f;
            float mn = (nn > 0.f) ? sneg / fmaxf(nn, 1.f) : 0.f;
            float pen = 1.f - mp + mn;
            sum_term += pen;
            if (c == CATS - 1) pen_last = pen;
        }
        // cel = mean(sp + (1-l)*sig); sum((1-l)*sig) = sum(sig) - sum(sig*l)
        float cel = (ws[3 * CATS] + (tot_ssig - tot_spos)) * invBC;
        out[0] = cel + 0.1f * (sum_term / 15.f);
        out[1] = 0.1f * pen_last;
    }
}

extern "C" void kernel_launch(void* const* d_in, const int* in_sizes, int n_in,
                              void* d_out, int out_size, void* d_ws, size_t ws_size,
                              hipStream_t stream) {
    const float* outp = (const float*)d_in[0];
    const float* labp = (const float*)d_in[1];
    float* out = (float*)d_out;
    float* ws  = (float*)d_ws;

    const int total   = in_sizes[0];          // B * 15
    const int nFloat4 = total / 4;
    const float rowsB = (float)(total / CATS);
    const float invBC = 1.0f / (float)total;

    // ws is re-poisoned before every timed launch -> zero it (capture-safe async memset)
    hipMemsetAsync(ws, 0, NSUMS * sizeof(float), stream);

    mauch_main<<<NBLOCKS, NTHREADS, 0, stream>>>(outp, labp, ws, nFloat4);
    mauch_final<<<1, 64, 0, stream>>>(ws, out, invBC, rowsB);
}

// Round 6
// 250.684 us; speedup vs baseline: 1.7673x; 1.0341x over previous
//
#include <hip/hip_runtime.h>

// MAUCHLoss: B=2097152 rows, C=15 categories, f32 inputs.
// ws layout (46 floats): [0..14] sum(sig) per cat, [15..29] sum(sig*label),
// [30..44] sum(label) (npos), [45] sum(softplus(-sig)) for CEL.
//
// R5 post-mortem: total now dominated by harness re-poison fills (~195 us
// fixed). main ~= 63 us (4.0 TB/s effective). VALU ~7 us -> memory path.
// Harness poisons 480 MiB of ws to 0xAA each iter -> L3 full of dirty
// lines -> our misses pay evict+writeback latency (~2x clean miss).
// R6: PF=8 (16 float4 loads in flight/thread, ~100 VGPR, still 4
// waves/SIMD so 960 blocks remain a single residency round).

#define CATS 15
#define NBLOCKS 960   // 960*256*4 = 983,040 = 15*65536 -> category phase constant per thread
#define NTHREADS 256
#define NSUMS (3 * CATS + 1)   // 46
#define PF 8                   // pipeline depth (iterations ahead)
#define ITERS 32               // nFloat4 / stride for the fixed problem size

typedef float vf4 __attribute__((ext_vector_type(4)));

__device__ __forceinline__ vf4 ntload4(const vf4* p) {
    return __builtin_nontemporal_load(p);
}

// softplus(-s) = log(1+exp(-s)) on s in (0,1): degree-4 poly, |err| < 1e-4.
__device__ __forceinline__ float softplus_neg_unit(float s) {
    const float c0 = 0.69314718f, c1 = -0.5f, c2 = 0.125f, c4 = -0.0048853f;
    float s2 = s * s;
    return c0 + fmaf(c1, s, fmaf(c2, s2, c4 * s2 * s2));
}

__device__ __forceinline__ void accum_elem(float x, float l,
                                           float& ssig, float& spos, float& snp,
                                           float& scel) {
    float e   = __expf(-x);                       // transcendental 1
    float sig = __builtin_amdgcn_rcpf(1.0f + e);  // transcendental 2
    ssig += sig;
    spos = fmaf(sig, l, spos);
    snp  += l;
    scel += softplus_neg_unit(sig);
}

__global__ __launch_bounds__(NTHREADS) void mauch_main(
    const float* __restrict__ outp, const float* __restrict__ labp,
    float* __restrict__ ws, int nFloat4)
{
    const int t = blockIdx.x * blockDim.x + threadIdx.x;
    const int stride = gridDim.x * blockDim.x;   // stride*4 % 15 == 0

    float ssig[4] = {0.f, 0.f, 0.f, 0.f};
    float spos[4] = {0.f, 0.f, 0.f, 0.f};
    float snp[4]  = {0.f, 0.f, 0.f, 0.f};
    float scel = 0.f;

    const vf4* o4 = (const vf4*)outp;
    const vf4* l4 = (const vf4*)labp;

    if (nFloat4 == ITERS * stride) {
        // fixed-size fast path: explicit PF-deep register pipeline
        vf4 ob[PF], lb[PF];
#pragma unroll
        for (int p = 0; p < PF; ++p) {
            ob[p] = ntload4(o4 + t + p * stride);
            lb[p] = ntload4(l4 + t + p * stride);
        }
#pragma unroll
        for (int i = 0; i < ITERS; ++i) {
            vf4 ov = ob[i % PF];
            vf4 lv = lb[i % PF];
            if (i + PF < ITERS) {
                ob[i % PF] = ntload4(o4 + t + (i + PF) * stride);
                lb[i % PF] = ntload4(l4 + t + (i + PF) * stride);
            }
#pragma unroll
            for (int j = 0; j < 4; ++j)
                accum_elem(ov[j], lv[j], ssig[j], spos[j], snp[j], scel);
        }
    } else {
        for (int f = t; f < nFloat4; f += stride) {
            vf4 ov = ntload4(o4 + f);
            vf4 lv = ntload4(l4 + f);
#pragma unroll
            for (int j = 0; j < 4; ++j)
                accum_elem(ov[j], lv[j], ssig[j], spos[j], snp[j], scel);
        }
    }

    // ---- block reduction in LDS ----
    __shared__ float red[NSUMS];
    for (int i = threadIdx.x; i < NSUMS; i += blockDim.x) red[i] = 0.f;
    __syncthreads();

    // element categories for this thread: (4t + j) mod 15, constant across iterations
    int base = (4 * t) % CATS;
#pragma unroll
    for (int j = 0; j < 4; ++j) {
        int c = base + j; if (c >= CATS) c -= CATS;
        atomicAdd(&red[c],            ssig[j]);
        atomicAdd(&red[CATS + c],     spos[j]);
        atomicAdd(&red[2 * CATS + c], snp[j]);
    }
    atomicAdd(&red[3 * CATS], scel);
    __syncthreads();

    // ---- global accumulation (device-scope atomics, no fence) ----
    if (threadIdx.x < NSUMS) atomicAdd(&ws[threadIdx.x], red[threadIdx.x]);
}

__global__ void mauch_final(const float* __restrict__ ws, float* __restrict__ out,
                            float invBC, float rowsB)
{
    if (threadIdx.x == 0 && blockIdx.x == 0) {
        float sum_term = 0.f, pen_last = 0.f;
        float tot_ssig = 0.f, tot_spos = 0.f;
#pragma unroll
        for (int c = 0; c < CATS; ++c) {
            float ssig = ws[c];
            float sp   = ws[CATS + c];
            float np   = ws[2 * CATS + c];
            float nn   = rowsB - np;
            float sneg = ssig - sp;
            tot_ssig += ssig;
            tot_spos += sp;
            float mp = (np > 0.f) ? sp   / fmaxf(np, 1.f) : 0.f;
            float mn = (nn > 0.f) ? sneg / fmaxf(nn, 1.f) : 0.f;
            float pen = 1.f - mp + mn;
            sum_term += pen;
            if (c == CATS - 1) pen_last = pen;
        }
        // cel = mean(sp + (1-l)*sig); sum((1-l)*sig) = sum(sig) - sum(sig*l)
        float cel = (ws[3 * CATS] + (tot_ssig - tot_spos)) * invBC;
        out[0] = cel + 0.1f * (sum_term / 15.f);
        out[1] = 0.1f * pen_last;
    }
}

extern "C" void kernel_launch(void* const* d_in, const int* in_sizes, int n_in,
                              void* d_out, int out_size, void* d_ws, size_t ws_size,
                              hipStream_t stream) {
    const float* outp = (const float*)d_in[0];
    const float* labp = (const float*)d_in[1];
    float* out = (float*)d_out;
    float* ws  = (float*)d_ws;

    const int total   = in_sizes[0];          // B * 15
    const int nFloat4 = total / 4;
    const float rowsB = (float)(total / CATS);
    const float invBC = 1.0f / (float)total;

    // ws is re-poisoned before every timed launch -> zero it (capture-safe async memset)
    hipMemsetAsync(ws, 0, NSUMS * sizeof(float), stream);

    mauch_main<<<NBLOCKS, NTHREADS, 0, stream>>>(outp, labp, ws, nFloat4);
    mauch_final<<<1, 64, 0, stream>>>(ws, out, invBC, rowsB);
}

// Round 7
// 248.697 us; speedup vs baseline: 1.7814x; 1.0080x over previous
//
#include <hip/hip_runtime.h>

// MAUCHLoss: B=2097152 rows, C=15 categories, f32 inputs.
// ws layout (46 floats): [0..14] sum(sig) per cat, [15..29] sum(sig*label),
// [30..44] sum(label) (npos), [45] sum(softplus(-sig)) for CEL.
//
// R6 post-mortem: PF=8 -> total 250.7 us (main ~55 us, ~4.6 TB/s effective).
// Latency-coverage model: coverage = PF * T_iter ~= 8*120 = 960 cyc, right
// at the ~900 cyc HBM-miss latency -> still partially stalled.
// R7: PF=10 (coverage ~1200 cyc > 900, VGPR ~112 stays under the 128
// cliff so 960 blocks remain one residency round at 4 waves/SIMD).

#define CATS 15
#define NBLOCKS 960   // 960*256*4 = 983,040 = 15*65536 -> category phase constant per thread
#define NTHREADS 256
#define NSUMS (3 * CATS + 1)   // 46
#define PF 10                  // pipeline depth (iterations ahead)
#define ITERS 32               // nFloat4 / stride for the fixed problem size

typedef float vf4 __attribute__((ext_vector_type(4)));

__device__ __forceinline__ vf4 ntload4(const vf4* p) {
    return __builtin_nontemporal_load(p);
}

// softplus(-s) = log(1+exp(-s)) on s in (0,1): degree-4 poly, |err| < 1e-4.
__device__ __forceinline__ float softplus_neg_unit(float s) {
    const float c0 = 0.69314718f, c1 = -0.5f, c2 = 0.125f, c4 = -0.0048853f;
    float s2 = s * s;
    return c0 + fmaf(c1, s, fmaf(c2, s2, c4 * s2 * s2));
}

__device__ __forceinline__ void accum_elem(float x, float l,
                                           float& ssig, float& spos, float& snp,
                                           float& scel) {
    float e   = __expf(-x);                       // transcendental 1
    float sig = __builtin_amdgcn_rcpf(1.0f + e);  // transcendental 2
    ssig += sig;
    spos = fmaf(sig, l, spos);
    snp  += l;
    scel += softplus_neg_unit(sig);
}

__global__ __launch_bounds__(NTHREADS) void mauch_main(
    const float* __restrict__ outp, const float* __restrict__ labp,
    float* __restrict__ ws, int nFloat4)
{
    const int t = blockIdx.x * blockDim.x + threadIdx.x;
    const int stride = gridDim.x * blockDim.x;   // stride*4 % 15 == 0

    float ssig[4] = {0.f, 0.f, 0.f, 0.f};
    float spos[4] = {0.f, 0.f, 0.f, 0.f};
    float snp[4]  = {0.f, 0.f, 0.f, 0.f};
    float scel = 0.f;

    const vf4* o4 = (const vf4*)outp;
    const vf4* l4 = (const vf4*)labp;

    if (nFloat4 == ITERS * stride) {
        // fixed-size fast path: explicit PF-deep register pipeline
        vf4 ob[PF], lb[PF];
#pragma unroll
        for (int p = 0; p < PF; ++p) {
            ob[p] = ntload4(o4 + t + p * stride);
            lb[p] = ntload4(l4 + t + p * stride);
        }
#pragma unroll
        for (int i = 0; i < ITERS; ++i) {
            vf4 ov = ob[i % PF];
            vf4 lv = lb[i % PF];
            if (i + PF < ITERS) {
                ob[i % PF] = ntload4(o4 + t + (i + PF) * stride);
                lb[i % PF] = ntload4(l4 + t + (i + PF) * stride);
            }
#pragma unroll
            for (int j = 0; j < 4; ++j)
                accum_elem(ov[j], lv[j], ssig[j], spos[j], snp[j], scel);
        }
    } else {
        for (int f = t; f < nFloat4; f += stride) {
            vf4 ov = ntload4(o4 + f);
            vf4 lv = ntload4(l4 + f);
#pragma unroll
            for (int j = 0; j < 4; ++j)
                accum_elem(ov[j], lv[j], ssig[j], spos[j], snp[j], scel);
        }
    }

    // ---- block reduction in LDS ----
    __shared__ float red[NSUMS];
    for (int i = threadIdx.x; i < NSUMS; i += blockDim.x) red[i] = 0.f;
    __syncthreads();

    // element categories for this thread: (4t + j) mod 15, constant across iterations
    int base = (4 * t) % CATS;
#pragma unroll
    for (int j = 0; j < 4; ++j) {
        int c = base + j; if (c >= CATS) c -= CATS;
        atomicAdd(&red[c],            ssig[j]);
        atomicAdd(&red[CATS + c],     spos[j]);
        atomicAdd(&red[2 * CATS + c], snp[j]);
    }
    atomicAdd(&red[3 * CATS], scel);
    __syncthreads();

    // ---- global accumulation (device-scope atomics, no fence) ----
    if (threadIdx.x < NSUMS) atomicAdd(&ws[threadIdx.x], red[threadIdx.x]);
}

__global__ void mauch_final(const float* __restrict__ ws, float* __restrict__ out,
                            float invBC, float rowsB)
{
    if (threadIdx.x == 0 && blockIdx.x == 0) {
        float sum_term = 0.f, pen_last = 0.f;
        float tot_ssig = 0.f, tot_spos = 0.f;
#pragma unroll
        for (int c = 0; c < CATS; ++c) {
            float ssig = ws[c];
            float sp   = ws[CATS + c];
            float np   = ws[2 * CATS + c];
            float nn   = rowsB - np;
            float sneg = ssig - sp;
            tot_ssig += ssig;
            tot_spos += sp;
            float mp = (np > 0.f) ? sp   / fmaxf(np, 1.f) : 0.f;
            float mn = (nn > 0.f) ? sneg / fmaxf(nn, 1.f) : 0.f;
            float pen = 1.f - mp + mn;
            sum_term += pen;
            if (c == CATS - 1) pen_last = pen;
        }
        // cel = mean(sp + (1-l)*sig); sum((1-l)*sig) = sum(sig) - sum(sig*l)
        float cel = (ws[3 * CATS] + (tot_ssig - tot_spos)) * invBC;
        out[0] = cel + 0.1f * (sum_term / 15.f);
        out[1] = 0.1f * pen_last;
    }
}

extern "C" void kernel_launch(void* const* d_in, const int* in_sizes, int n_in,
                              void* d_out, int out_size, void* d_ws, size_t ws_size,
                              hipStream_t stream) {
    const float* outp = (const float*)d_in[0];
    const float* labp = (const float*)d_in[1];
    float* out = (float*)d_out;
    float* ws  = (float*)d_ws;

    const int total   = in_sizes[0];          // B * 15
    const int nFloat4 = total / 4;
    const float rowsB = (float)(total / CATS);
    const float invBC = 1.0f / (float)total;

    // ws is re-poisoned before every timed launch -> zero it (capture-safe async memset)
    hipMemsetAsync(ws, 0, NSUMS * sizeof(float), stream);

    mauch_main<<<NBLOCKS, NTHREADS, 0, stream>>>(outp, labp, ws, nFloat4);
    mauch_final<<<1, 64, 0, stream>>>(ws, out, invBC, rowsB);
}